// Round 2
// baseline (93.269 us; speedup 1.0000x reference)
//
#include <hip/hip_runtime.h>
#include <math.h>

#define NN 1024
#define DD 64
#define MIN_NORM 1e-15f
#define ART_BOUND (1.0f - 1e-7f)

__device__ __forceinline__ float wave_sum(float v) {
#pragma unroll
    for (int off = 32; off >= 1; off >>= 1)
        v += __shfl_xor(v, off, 64);
    return v;
}

__device__ __forceinline__ float artanh_f(float z) {
    z = fminf(z, ART_BOUND);
    return 0.5f * logf((1.0f + z) / (1.0f - z));
}

// Per-point precompute: x2[i] = ||x_i||^2, left[i] = x_tan_i . W[:D] + b,
// right[i] = x_tan_i . W[D:].  One wave per row, lane = dim.
__global__ __launch_bounds__(64) void hypagg_pre_kernel(
    const float* __restrict__ x, const float* __restrict__ W,
    const float* __restrict__ b, float* __restrict__ x2_out,
    float* __restrict__ left_out, float* __restrict__ right_out) {
    const int i = blockIdx.x;
    const int d = threadIdx.x;
    const float xd = x[i * DD + d];
    const float x2 = wave_sum(xd * xd);
    const float pn = fmaxf(sqrtf(x2), MIN_NORM);
    const float xt = artanh_f(pn) * xd / pn;  // logmap0(x)_d  (sqrt_c = 1)
    const float l = wave_sum(xt * W[d]);
    const float r = wave_sum(xt * W[DD + d]);
    if (d == 0) {
        x2_out[i] = x2;
        left_out[i] = l + b[0];
        right_out[i] = r;
    }
}

// Main aggregation: block = row i, lane = dim d.
__global__ __launch_bounds__(64) void hypagg_main_kernel(
    const float* __restrict__ x, const float* __restrict__ adj,
    const float* __restrict__ x2v, const float* __restrict__ leftv,
    const float* __restrict__ rightv, float* __restrict__ out) {
    const int i = blockIdx.x;
    const int lane = threadIdx.x;

    const float xi = x[i * DD + lane];
    const float x2i = x2v[i];
    const float li = leftv[i];
    const float Bc = 1.0f - x2i;                 // (1 - c*x2_i)
    const float fac_i = fmaxf(Bc, MIN_NORM);     // 2/(sqrt_c*lambda_i)

    float acc = 0.0f;                            // support_t row i (lane=dim)

#pragma unroll 1
    for (int k = 0; k < NN / 64; ++k) {
        const float av = adj[i * NN + k * 64 + lane];
        unsigned long long mask = __ballot(av != 0.0f);
        while (mask) {
            const int bit = __builtin_ctzll(mask);
            mask &= mask - 1;
            const int j = k * 64 + bit;
            const float adjv = __shfl(av, bit, 64);
            const float xj = x[j * DD + lane];
            const float y2 = x2v[j];
            const float rj = rightv[j];
            // sub = mobius_add(-x_i, x_j):  xy = -(x_i . x_j)
            const float dotij = wave_sum(xi * xj);
            const float xy = -dotij;
            const float A = 1.0f + 2.0f * xy + y2;
            float den = 1.0f + 2.0f * xy + x2i * y2;
            den = fmaxf(den, MIN_NORM);
            const float sub = (A * (-xi) + Bc * xj) / den;
            const float sn2 = wave_sum(sub * sub);
            const float sn = fmaxf(sqrtf(sn2), MIN_NORM);
            const float factor = fac_i * artanh_f(sn) / sn;
            const float z = li + rj;
            const float w = adjv / (1.0f + expf(-z));  // sigmoid * adj
            acc += w * factor * sub;
        }
    }

    // Epilogue — NOTE the HGCN argument order: _expmap(u=x, p=support_t):
    // exp at point p=acc of "tangent" u=x_i, then proj.
    const float p2 = wave_sum(acc * acc);                 // ||support_t||^2
    const float un = fmaxf(sqrtf(x2i), MIN_NORM);         // ||x_i||
    const float lam_p = 2.0f / fmaxf(1.0f - p2, MIN_NORM);
    const float t = tanhf(lam_p * un * 0.5f);
    const float second = t * xi / un;                     // tanh(..)*u/(sqrt_c*un)
    // mobius_add(p=acc, y=second)
    const float y2 = wave_sum(second * second);
    const float xy = wave_sum(acc * second);
    const float A = 1.0f + 2.0f * xy + y2;
    float den = 1.0f + 2.0f * xy + p2 * y2;
    den = fmaxf(den, MIN_NORM);
    const float res = (A * acc + (1.0f - p2) * second) / den;
    // proj
    const float n2 = wave_sum(res * res);
    const float n = fmaxf(sqrtf(n2), MIN_NORM);
    const float maxnorm = 1.0f - 4e-3f;
    const float o = (n > maxnorm) ? res * (maxnorm / n) : res;
    out[i * DD + lane] = o;
}

extern "C" void kernel_launch(void* const* d_in, const int* in_sizes, int n_in,
                              void* d_out, int out_size, void* d_ws, size_t ws_size,
                              hipStream_t stream) {
    const float* x   = (const float*)d_in[0];
    const float* adj = (const float*)d_in[1];
    const float* W   = (const float*)d_in[2];
    const float* b   = (const float*)d_in[3];
    float* out = (float*)d_out;

    float* x2v    = (float*)d_ws;       // N floats
    float* leftv  = x2v + NN;           // N floats
    float* rightv = leftv + NN;         // N floats

    hipLaunchKernelGGL(hypagg_pre_kernel, dim3(NN), dim3(DD), 0, stream,
                       x, W, b, x2v, leftv, rightv);
    hipLaunchKernelGGL(hypagg_main_kernel, dim3(NN), dim3(DD), 0, stream,
                       x, adj, x2v, leftv, rightv, out);
}

// Round 3
// 77.482 us; speedup vs baseline: 1.2037x; 1.2037x over previous
//
#include <hip/hip_runtime.h>
#include <math.h>

#define NN 1024
#define DD 64
#define MIN_NORM 1e-15f
#define ART_BOUND (1.0f - 1e-7f)

__device__ __forceinline__ float wave_sum(float v) {
#pragma unroll
    for (int off = 32; off >= 1; off >>= 1)
        v += __shfl_xor(v, off, 64);
    return v;
}

__device__ __forceinline__ void wave_sum4(float& a, float& b, float& c, float& d) {
#pragma unroll
    for (int off = 32; off >= 1; off >>= 1) {
        a += __shfl_xor(a, off, 64);
        b += __shfl_xor(b, off, 64);
        c += __shfl_xor(c, off, 64);
        d += __shfl_xor(d, off, 64);
    }
}

__device__ __forceinline__ float artanh_f(float z) {
    z = fminf(z, ART_BOUND);
    return 0.5f * __logf((1.0f + z) / (1.0f - z));
}

// Per-point precompute: x2[i], left[i] = x_tan_i.W[:D]+b, right[i] = x_tan_i.W[D:]
__global__ __launch_bounds__(64) void hypagg_pre_kernel(
    const float* __restrict__ x, const float* __restrict__ W,
    const float* __restrict__ b, float* __restrict__ x2_out,
    float* __restrict__ left_out, float* __restrict__ right_out) {
    const int i = blockIdx.x;
    const int d = threadIdx.x;
    const float xd = x[i * DD + d];
    const float x2 = wave_sum(xd * xd);
    const float pn = fmaxf(sqrtf(x2), MIN_NORM);
    const float xt = artanh_f(pn) * xd / pn;  // logmap0(x)_d  (sqrt_c = 1)
    const float l = wave_sum(xt * W[d]);
    const float r = wave_sum(xt * W[DD + d]);
    if (d == 0) {
        x2_out[i] = x2;
        left_out[i] = l + b[0];
        right_out[i] = r;
    }
}

// Main aggregation: block = row i, lane = dim d.
// Key algebra: sub_j = (-A_j*x_i + Bc*x_j)/den_j with scalars
//   A_j = 1 - 2*dot_ij + y2_j, den_j = 1 - 2*dot_ij + x2i*y2_j, Bc = 1 - x2i.
// ||sub_j||^2 = (A^2*x2i - 2*A*Bc*dot + Bc^2*y2)/den^2  -> no 2nd reduction.
// acc_d = alpha*x_i[d] + Bc * sum_j gamma_j * x_j[d].
__global__ __launch_bounds__(64) void hypagg_main_kernel(
    const float* __restrict__ x, const float* __restrict__ adj,
    const float* __restrict__ x2v, const float* __restrict__ leftv,
    const float* __restrict__ rightv, float* __restrict__ out) {
    __shared__ int   sj[NN];
    __shared__ float sw[NN];
    __shared__ float sy[NN];

    const int i = blockIdx.x;
    const int lane = threadIdx.x;

    const float xi = x[i * DD + lane];
    const float x2i = x2v[i];
    const float li = leftv[i];
    const float Bc = 1.0f - x2i;
    const float fac_i = fmaxf(Bc, MIN_NORM);  // 2/(sqrt_c*lambda_i)

    // Load the whole adj row up-front (one latency, not 16 serial ones).
    float av[16];
#pragma unroll
    for (int k = 0; k < 16; ++k) av[k] = adj[i * NN + k * 64 + lane];

    // Stage compacted neighbor list into LDS: index, w = adj*sigmoid(li+r_j), y2_j.
    int base = 0;
#pragma unroll
    for (int k = 0; k < 16; ++k) {
        const unsigned long long m = __ballot(av[k] != 0.0f);
        if (av[k] != 0.0f) {
            const int pos = __builtin_amdgcn_mbcnt_hi(
                (unsigned int)(m >> 32),
                __builtin_amdgcn_mbcnt_lo((unsigned int)m, 0u));
            const int j = k * 64 + lane;
            const int s = base + pos;
            sj[s] = j;
            sy[s] = x2v[j];
            sw[s] = av[k] / (1.0f + __expf(-(li + rightv[j])));
        }
        base += __popcll(m);
    }
    __syncthreads();
    const int M = base;

    float Sd = 0.0f;     // sum_j gamma_j * x_j[d]
    float alpha = 0.0f;  // sum_j -gamma_j * A_j

    int t = 0;
    for (; t + 4 <= M; t += 4) {
        const int j0 = sj[t], j1 = sj[t + 1], j2 = sj[t + 2], j3 = sj[t + 3];
        const float xa = x[j0 * DD + lane];
        const float xb = x[j1 * DD + lane];
        const float xc = x[j2 * DD + lane];
        const float xd = x[j3 * DD + lane];
        float d0 = xi * xa, d1 = xi * xb, d2 = xi * xc, d3 = xi * xd;
        wave_sum4(d0, d1, d2, d3);
#pragma unroll
        for (int q = 0; q < 4; ++q) {
            const float dot = (q == 0) ? d0 : (q == 1) ? d1 : (q == 2) ? d2 : d3;
            const float y2 = sy[t + q];
            const float w = sw[t + q];
            const float A = 1.0f - 2.0f * dot + y2;
            const float den = fmaxf(1.0f - 2.0f * dot + x2i * y2, MIN_NORM);
            const float sn2 = (A * A * x2i - 2.0f * A * Bc * dot + Bc * Bc * y2) / (den * den);
            const float sn = sqrtf(fmaxf(sn2, 0.0f));
            const float snc = fmaxf(sn, MIN_NORM);
            const float g = w * fac_i * artanh_f(sn) / (snc * den);
            const float xq = (q == 0) ? xa : (q == 1) ? xb : (q == 2) ? xc : xd;
            Sd += g * xq;
            alpha -= g * A;
        }
    }
    for (; t < M; ++t) {
        const int j = sj[t];
        const float xj = x[j * DD + lane];
        const float dot = wave_sum(xi * xj);
        const float y2 = sy[t];
        const float w = sw[t];
        const float A = 1.0f - 2.0f * dot + y2;
        const float den = fmaxf(1.0f - 2.0f * dot + x2i * y2, MIN_NORM);
        const float sn2 = (A * A * x2i - 2.0f * A * Bc * dot + Bc * Bc * y2) / (den * den);
        const float sn = sqrtf(fmaxf(sn2, 0.0f));
        const float snc = fmaxf(sn, MIN_NORM);
        const float g = w * fac_i * artanh_f(sn) / (snc * den);
        Sd += g * xj;
        alpha -= g * A;
    }

    const float accd = alpha * xi + Bc * Sd;  // support_t row i, lane = dim

    // Epilogue — HGCN arg order: _expmap(u=x_i, p=acc), then proj.
    const float p2 = wave_sum(accd * accd);
    const float un = fmaxf(sqrtf(x2i), MIN_NORM);
    const float lam_p = 2.0f / fmaxf(1.0f - p2, MIN_NORM);
    const float tt = tanhf(lam_p * un * 0.5f);
    const float second = tt * xi / un;
    const float y2e = wave_sum(second * second);
    const float xye = wave_sum(accd * second);
    const float Ae = 1.0f + 2.0f * xye + y2e;
    const float dene = fmaxf(1.0f + 2.0f * xye + p2 * y2e, MIN_NORM);
    const float res = (Ae * accd + (1.0f - p2) * second) / dene;
    const float n2 = wave_sum(res * res);
    const float n = fmaxf(sqrtf(n2), MIN_NORM);
    const float maxnorm = 1.0f - 4e-3f;
    const float o = (n > maxnorm) ? res * (maxnorm / n) : res;
    out[i * DD + lane] = o;
}

extern "C" void kernel_launch(void* const* d_in, const int* in_sizes, int n_in,
                              void* d_out, int out_size, void* d_ws, size_t ws_size,
                              hipStream_t stream) {
    const float* x   = (const float*)d_in[0];
    const float* adj = (const float*)d_in[1];
    const float* W   = (const float*)d_in[2];
    const float* b   = (const float*)d_in[3];
    float* out = (float*)d_out;

    float* x2v    = (float*)d_ws;       // N floats
    float* leftv  = x2v + NN;           // N floats
    float* rightv = leftv + NN;         // N floats

    hipLaunchKernelGGL(hypagg_pre_kernel, dim3(NN), dim3(DD), 0, stream,
                       x, W, b, x2v, leftv, rightv);
    hipLaunchKernelGGL(hypagg_main_kernel, dim3(NN), dim3(DD), 0, stream,
                       x, adj, x2v, leftv, rightv, out);
}

// Round 5
// 73.936 us; speedup vs baseline: 1.2615x; 1.0480x over previous
//
#include <hip/hip_runtime.h>
#include <math.h>

#define NN 1024
#define DD 64
#define MIN_NORM 1e-15f
#define ART_BOUND (1.0f - 1e-7f)

__device__ __forceinline__ float wave_sum(float v) {
#pragma unroll
    for (int off = 32; off >= 1; off >>= 1)
        v += __shfl_xor(v, off, 64);
    return v;
}

__device__ __forceinline__ float artanh_f(float z) {
    z = fminf(z, ART_BOUND);
    return 0.5f * __logf((1.0f + z) / (1.0f - z));
}

// Per-point precompute (UNCHANGED from the passing R2 kernel):
// x2[i], left[i] = x_tan_i.W[:D]+b, right[i] = x_tan_i.W[D:]
__global__ __launch_bounds__(64) void hypagg_pre_kernel(
    const float* __restrict__ x, const float* __restrict__ W,
    const float* __restrict__ b, float* __restrict__ x2_out,
    float* __restrict__ left_out, float* __restrict__ right_out) {
    const int i = blockIdx.x;
    const int d = threadIdx.x;
    const float xd = x[i * DD + d];
    const float x2 = wave_sum(xd * xd);
    const float pn = fmaxf(sqrtf(x2), MIN_NORM);
    const float xt = artanh_f(pn) * xd / pn;  // logmap0(x)_d  (sqrt_c = 1)
    const float l = wave_sum(xt * W[d]);
    const float r = wave_sum(xt * W[DD + d]);
    if (d == 0) {
        x2_out[i] = x2;
        left_out[i] = l + b[0];
        right_out[i] = r;
    }
}

// Main aggregation: one block (4 waves) per row i; wave w owns adjacency
// chunks k = 4w .. 4w+3 with R2's PROVEN contiguous mapping j = k*64 + bit.
// Per-neighbor math is verbatim R2 (passed, absmax 4.9e-4). New vs R2:
// only the 4-way partial split + LDS combine + wave-0 epilogue.
__global__ __launch_bounds__(256) void hypagg_main_kernel(
    const float* __restrict__ x, const float* __restrict__ adj,
    const float* __restrict__ x2v, const float* __restrict__ leftv,
    const float* __restrict__ rightv, float* __restrict__ out) {
    __shared__ float sSd[4][DD];
    __shared__ float sAl[4];

    const int i = blockIdx.x;
    const int tid = threadIdx.x;
    const int w = tid >> 6;      // wave id 0..3
    const int lane = tid & 63;   // dim

    const float xi = x[i * DD + lane];
    const float x2i = x2v[i];
    const float li = leftv[i];
    const float Bc = 1.0f - x2i;
    const float fac_i = fmaxf(Bc, MIN_NORM);  // 2/(sqrt_c*lambda_i)

    // Batched adj row load for this wave's 4 chunks (one latency).
    float av[4];
#pragma unroll
    for (int kk = 0; kk < 4; ++kk)
        av[kk] = adj[i * NN + (4 * w + kk) * 64 + lane];

    float Sd = 0.0f;     // sum_j g_j * x_j[d]   (per-lane)
    float alpha = 0.0f;  // sum_j -g_j * A_j     (wave-uniform)

#pragma unroll
    for (int kk = 0; kk < 4; ++kk) {
        unsigned long long mask = __ballot(av[kk] != 0.0f);
        while (mask) {
            const int bit = __builtin_ctzll(mask);
            mask &= mask - 1;
            const int j = (4 * w + kk) * 64 + bit;   // R2's proven mapping
            const float adjv = __shfl(av[kk], bit, 64);
            const float xj = x[j * DD + lane];
            const float y2 = x2v[j];
            const float rj = rightv[j];
            const float dot = wave_sum(xi * xj);
            const float wgt = adjv / (1.0f + __expf(-(li + rj)));
            const float A = 1.0f - 2.0f * dot + y2;
            const float den = fmaxf(1.0f - 2.0f * dot + x2i * y2, MIN_NORM);
            const float sn2 = (A * A * x2i - 2.0f * A * Bc * dot + Bc * Bc * y2) / (den * den);
            const float sn = sqrtf(fmaxf(sn2, 0.0f));
            const float snc = fmaxf(sn, MIN_NORM);
            const float g = wgt * fac_i * artanh_f(sn) / (snc * den);
            Sd += g * xj;
            alpha -= g * A;
        }
    }

    sSd[w][lane] = Sd;
    if (lane == 0) sAl[w] = alpha;
    __syncthreads();

    if (w == 0) {
        const float S = sSd[0][lane] + sSd[1][lane] + sSd[2][lane] + sSd[3][lane];
        const float al = sAl[0] + sAl[1] + sAl[2] + sAl[3];
        const float accd = al * xi + Bc * S;  // support_t row i, lane = dim

        // Epilogue (verbatim R2) — HGCN arg order: _expmap(u=x_i, p=acc), proj.
        const float p2 = wave_sum(accd * accd);
        const float un = fmaxf(sqrtf(x2i), MIN_NORM);
        const float lam_p = 2.0f / fmaxf(1.0f - p2, MIN_NORM);
        const float tt = tanhf(lam_p * un * 0.5f);
        const float second = tt * xi / un;
        const float y2e = wave_sum(second * second);
        const float xye = wave_sum(accd * second);
        const float Ae = 1.0f + 2.0f * xye + y2e;
        const float dene = fmaxf(1.0f + 2.0f * xye + p2 * y2e, MIN_NORM);
        const float res = (Ae * accd + (1.0f - p2) * second) / dene;
        const float n2 = wave_sum(res * res);
        const float n = fmaxf(sqrtf(n2), MIN_NORM);
        const float maxnorm = 1.0f - 4e-3f;
        const float o = (n > maxnorm) ? res * (maxnorm / n) : res;
        out[i * DD + lane] = o;
    }
}

extern "C" void kernel_launch(void* const* d_in, const int* in_sizes, int n_in,
                              void* d_out, int out_size, void* d_ws, size_t ws_size,
                              hipStream_t stream) {
    const float* x   = (const float*)d_in[0];
    const float* adj = (const float*)d_in[1];
    const float* W   = (const float*)d_in[2];
    const float* b   = (const float*)d_in[3];
    float* out = (float*)d_out;

    float* x2v    = (float*)d_ws;       // N floats
    float* leftv  = x2v + NN;           // N floats
    float* rightv = leftv + NN;         // N floats

    hipLaunchKernelGGL(hypagg_pre_kernel, dim3(NN), dim3(DD), 0, stream,
                       x, W, b, x2v, leftv, rightv);
    hipLaunchKernelGGL(hypagg_main_kernel, dim3(NN), dim3(256), 0, stream,
                       x, adj, x2v, leftv, rightv, out);
}

// Round 9
// 73.220 us; speedup vs baseline: 1.2738x; 1.0098x over previous
//
#include <hip/hip_runtime.h>
#include <math.h>

#define NN 1024
#define DD 64
#define MIN_NORM 1e-15f
#define ART_BOUND (1.0f - 1e-7f)

__device__ __forceinline__ float wave_sum(float v) {
#pragma unroll
    for (int off = 32; off >= 1; off >>= 1)
        v += __shfl_xor(v, off, 64);
    return v;
}

__device__ __forceinline__ float artanh_f(float z) {
    z = fminf(z, ART_BOUND);
    return 0.5f * __logf((1.0f + z) / (1.0f - z));
}

// Pre-kernel: BITWISE-identical per-row arithmetic to the R2/R5 passing
// version; only packing changed (4 rows per 256-thread block, wave = row).
__global__ __launch_bounds__(256) void hypagg_pre_kernel(
    const float* __restrict__ x, const float* __restrict__ W,
    const float* __restrict__ b, float* __restrict__ x2_out,
    float* __restrict__ left_out, float* __restrict__ right_out) {
    const int i = blockIdx.x * 4 + (threadIdx.x >> 6);
    const int d = threadIdx.x & 63;
    const float xd = x[i * DD + d];
    const float x2 = wave_sum(xd * xd);
    const float pn = fmaxf(sqrtf(x2), MIN_NORM);
    const float xt = artanh_f(pn) * xd / pn;  // logmap0(x)_d  (sqrt_c = 1)
    const float l = wave_sum(xt * W[d]);
    const float r = wave_sum(xt * W[DD + d]);
    if (d == 0) {
        x2_out[i] = x2;
        left_out[i] = l + b[0];
        right_out[i] = r;
    }
}

// Main: R5's proven structure (4 waves/row, table scalars, wave-0 epilogue)
// + R2's proven LDS compaction and interleaved-dot ILP (R2 and R5 produced
// identical absmax 4.882812e-04 => these transforms are value-safe).
// Per-pair scalar math is verbatim R5. No inline scalar recomputation
// (that path failed in R4/R6/R7/R8 — artanh cliff, see journal).
__global__ __launch_bounds__(256) void hypagg_main_kernel(
    const float* __restrict__ x, const float* __restrict__ adj,
    const float* __restrict__ x2v, const float* __restrict__ leftv,
    const float* __restrict__ rightv, float* __restrict__ out) {
    __shared__ int   sjL[4][256];
    __shared__ float saL[4][256];
    __shared__ float sSd[4][DD];
    __shared__ float sAl[4];

    const int i = blockIdx.x;
    const int tid = threadIdx.x;
    const int w = tid >> 6;      // wave id 0..3
    const int lane = tid & 63;   // dim

    // Hoisted loads (scheduling only; values untouched).
    const float xi = x[i * DD + lane];
    const float x2i = x2v[i];
    const float li = leftv[i];
    float av[4];
#pragma unroll
    for (int kk = 0; kk < 4; ++kk)
        av[kk] = adj[i * NN + (4 * w + kk) * 64 + lane];

    const float Bc = 1.0f - x2i;
    const float fac_i = fmaxf(Bc, MIN_NORM);  // 2/(sqrt_c*lambda_i)

    // R2-proven ballot+mbcnt compaction (preserves j order within wave).
    int base = 0;
#pragma unroll
    for (int kk = 0; kk < 4; ++kk) {
        const unsigned long long m = __ballot(av[kk] != 0.0f);
        if (av[kk] != 0.0f) {
            const int pos = __builtin_amdgcn_mbcnt_hi(
                (unsigned int)(m >> 32),
                __builtin_amdgcn_mbcnt_lo((unsigned int)m, 0u));
            sjL[w][base + pos] = (4 * w + kk) * 64 + lane;
            saL[w][base + pos] = av[kk];
        }
        base += __popcll(m);
    }
    const int M = base;  // wave-uniform; same-wave LDS RAW, no barrier needed

    float Sd = 0.0f;     // sum_j g_j * x_j[d]   (per-lane)
    float alpha = 0.0f;  // sum_j -g_j * A_j     (wave-uniform)

    int t = 0;
    for (; t + 2 <= M; t += 2) {
        const int ja = sjL[w][t], jb = sjL[w][t + 1];
        const float aa = saL[w][t], ab = saL[w][t + 1];
        const float xa = x[ja * DD + lane];
        const float xb = x[jb * DD + lane];
        const float y2a = x2v[ja], y2b = x2v[jb];
        const float rja = rightv[ja], rjb = rightv[jb];
        // Two independent dot butterflies, interleaved (R2-proven pattern).
        float da = xi * xa, db = xi * xb;
#pragma unroll
        for (int off = 32; off >= 1; off >>= 1) {
            da += __shfl_xor(da, off, 64);
            db += __shfl_xor(db, off, 64);
        }
#pragma unroll
        for (int q = 0; q < 2; ++q) {
            const float dot = (q == 0) ? da : db;
            const float y2 = (q == 0) ? y2a : y2b;
            const float rj = (q == 0) ? rja : rjb;
            const float adjv = (q == 0) ? aa : ab;
            const float xq = (q == 0) ? xa : xb;
            const float wgt = adjv / (1.0f + __expf(-(li + rj)));
            const float A = 1.0f - 2.0f * dot + y2;
            const float den = fmaxf(1.0f - 2.0f * dot + x2i * y2, MIN_NORM);
            const float sn2 = (A * A * x2i - 2.0f * A * Bc * dot + Bc * Bc * y2) / (den * den);
            const float sn = sqrtf(fmaxf(sn2, 0.0f));
            const float snc = fmaxf(sn, MIN_NORM);
            const float g = wgt * fac_i * artanh_f(sn) / (snc * den);
            Sd += g * xq;
            alpha -= g * A;
        }
    }
    for (; t < M; ++t) {  // remainder: verbatim R5 body
        const int j = sjL[w][t];
        const float adjv = saL[w][t];
        const float xj = x[j * DD + lane];
        const float y2 = x2v[j];
        const float rj = rightv[j];
        const float dot = wave_sum(xi * xj);
        const float wgt = adjv / (1.0f + __expf(-(li + rj)));
        const float A = 1.0f - 2.0f * dot + y2;
        const float den = fmaxf(1.0f - 2.0f * dot + x2i * y2, MIN_NORM);
        const float sn2 = (A * A * x2i - 2.0f * A * Bc * dot + Bc * Bc * y2) / (den * den);
        const float sn = sqrtf(fmaxf(sn2, 0.0f));
        const float snc = fmaxf(sn, MIN_NORM);
        const float g = wgt * fac_i * artanh_f(sn) / (snc * den);
        Sd += g * xj;
        alpha -= g * A;
    }

    sSd[w][lane] = Sd;
    if (lane == 0) sAl[w] = alpha;
    __syncthreads();

    if (w == 0) {
        const float S = sSd[0][lane] + sSd[1][lane] + sSd[2][lane] + sSd[3][lane];
        const float al = sAl[0] + sAl[1] + sAl[2] + sAl[3];
        const float accd = al * xi + Bc * S;  // support_t row i, lane = dim

        // Epilogue (verbatim R5) — HGCN arg order: _expmap(u=x_i, p=acc).
        const float p2 = wave_sum(accd * accd);
        const float un = fmaxf(sqrtf(x2i), MIN_NORM);
        const float lam_p = 2.0f / fmaxf(1.0f - p2, MIN_NORM);
        const float tt = tanhf(lam_p * un * 0.5f);
        const float second = tt * xi / un;
        const float y2e = wave_sum(second * second);
        const float xye = wave_sum(accd * second);
        const float Ae = 1.0f + 2.0f * xye + y2e;
        const float dene = fmaxf(1.0f + 2.0f * xye + p2 * y2e, MIN_NORM);
        const float res = (Ae * accd + (1.0f - p2) * second) / dene;
        const float n2 = wave_sum(res * res);
        const float n = fmaxf(sqrtf(n2), MIN_NORM);
        const float maxnorm = 1.0f - 4e-3f;
        const float o = (n > maxnorm) ? res * (maxnorm / n) : res;
        out[i * DD + lane] = o;
    }
}

extern "C" void kernel_launch(void* const* d_in, const int* in_sizes, int n_in,
                              void* d_out, int out_size, void* d_ws, size_t ws_size,
                              hipStream_t stream) {
    const float* x   = (const float*)d_in[0];
    const float* adj = (const float*)d_in[1];
    const float* W   = (const float*)d_in[2];
    const float* b   = (const float*)d_in[3];
    float* out = (float*)d_out;

    float* x2v    = (float*)d_ws;       // N floats
    float* leftv  = x2v + NN;           // N floats
    float* rightv = leftv + NN;         // N floats

    hipLaunchKernelGGL(hypagg_pre_kernel, dim3(NN / 4), dim3(256), 0, stream,
                       x, W, b, x2v, leftv, rightv);
    hipLaunchKernelGGL(hypagg_main_kernel, dim3(NN), dim3(256), 0, stream,
                       x, adj, x2v, leftv, rightv, out);
}